// Round 1
// baseline (208.140 us; speedup 1.0000x reference)
//
#include <hip/hip_runtime.h>
#include <hip/hip_bf16.h>

#define B_  16
#define N_  16
#define H_  640
#define W_  640
#define HP_ 300
#define WP_ 300
#define IMG_FLOATS (H_ * W_ * 3)          // 1,228,800 per image
#define ALL_FLOATS (B_ * IMG_FLOATS)      // 19,660,800
#define PBOX_OFF   ALL_FLOATS

// boxinfo layout in d_ws: per entry e in [0,256): 8 ints
//   [0]=y0i [1]=x0i [2]=s [3]=valid [4]=d0(rot90) [5]=d1(flip_lr) [6]=d2(flip_ud) [7]=pad

__global__ __launch_bounds__(256) void prep_kernel(
    const float* __restrict__ boxes,          // [B,N,4] ymin,xmin,h,w
    const unsigned char* __restrict__ dec_raw, // [B,N,3] bool/int32/float32 (detected)
    float* __restrict__ pboxes_out,           // d_out + PBOX_OFF, [B,N,4]
    int* __restrict__ info)                   // d_ws, 256*8 ints
{
    __shared__ int s_nonzero_off;  // any nonzero byte at i%4 != 0
    __shared__ int s_floatpat;     // any byte == 0x3F or 0x80 (f32 1.0 pattern)
    if (threadIdx.x == 0) { s_nonzero_off = 0; s_floatpat = 0; }
    __syncthreads();
    // First 768 bytes are in-bounds under every candidate layout.
    for (int i = threadIdx.x; i < B_ * N_ * 3; i += blockDim.x) {
        unsigned char by = dec_raw[i];
        if ((i & 3) != 0 && by != 0) atomicOr(&s_nonzero_off, 1);
        if (by == 0x3F || by == 0x80) atomicOr(&s_floatpat, 1);
    }
    __syncthreads();
    int mode;                    // 0 = 1-byte bool, 1 = int32, 2 = float32
    if (!s_nonzero_off)      mode = 1;
    else if (s_floatpat)     mode = 2;
    else                     mode = 0;

    int t = threadIdx.x;         // entry index, one per (b,n)
    if (t < B_ * N_) {
        float ymin = boxes[t * 4 + 0];
        float xmin = boxes[t * 4 + 1];
        float h    = boxes[t * 4 + 2];
        float w    = boxes[t * 4 + 3];
        // Patcher.create(): scale*h square at box center-origin, clamp to image
        float ph = h * 0.2f;
        float pw = 1.0f * ph;                 // ASPECT = 1
        float y0 = ymin + h * 0.5f;           // ORIGIN[1]
        float x0 = xmin + w * 0.5f;           // ORIGIN[0]
        if (y0 + ph > (float)H_) y0 = (float)H_ - ph;
        if (x0 + pw > (float)W_) x0 = (float)W_ - pw;
        pboxes_out[t * 4 + 0] = y0;
        pboxes_out[t * 4 + 1] = x0;
        pboxes_out[t * 4 + 2] = ph;
        pboxes_out[t * 4 + 3] = pw;

        int y0i = (int)y0;                    // tf.cast truncation
        int x0i = (int)x0;
        int phi = (int)ph;
        int pwi = (int)pw;
        int valid = (phi * pwi) > 400;        // AREA_THRESH
        int s = phi > 1 ? phi : 1;            // jnp.maximum(box[2], 1)

        int d0, d1, d2;
        if (mode == 0) {
            d0 = dec_raw[t * 3 + 0] != 0;
            d1 = dec_raw[t * 3 + 1] != 0;
            d2 = dec_raw[t * 3 + 2] != 0;
        } else if (mode == 1) {
            const int* di = (const int*)dec_raw;
            d0 = di[t * 3 + 0] != 0;
            d1 = di[t * 3 + 1] != 0;
            d2 = di[t * 3 + 2] != 0;
        } else {
            const float* df = (const float*)dec_raw;
            d0 = df[t * 3 + 0] != 0.0f;
            d1 = df[t * 3 + 1] != 0.0f;
            d2 = df[t * 3 + 2] != 0.0f;
        }
        int* e = info + t * 8;
        e[0] = y0i; e[1] = x0i; e[2] = s; e[3] = valid;
        e[4] = d0;  e[5] = d1;  e[6] = d2; e[7] = 0;
    }
}

__global__ __launch_bounds__(256) void copy_kernel(
    const float4* __restrict__ in, float4* __restrict__ out, int n4)
{
    int stride = gridDim.x * blockDim.x;
    for (int i = blockIdx.x * blockDim.x + threadIdx.x; i < n4; i += stride)
        out[i] = in[i];
}

__global__ __launch_bounds__(256) void patch_kernel(
    const float* __restrict__ patch,  // [300,300,3]
    const int* __restrict__ info,     // 256*8 ints
    float* __restrict__ out)          // [B,H,W,3]
{
    int e = blockIdx.x;               // (b,n) entry
    int b = e >> 4;
    int n = e & 15;

    // this block's box
    const int* my = info + e * 8;
    int valid = my[3];
    if (!valid) return;               // wave-uniform
    int y0 = my[0], x0 = my[1], s = my[2];
    int d0 = my[4], d1 = my[5], d2 = my[6];

    // all 16 boxes of this image (for later-write-wins suppression)
    __shared__ int ly0[N_], lx0[N_], ls[N_], lact[N_];
    if (threadIdx.x < N_) {
        const int* o = info + (b * N_ + threadIdx.x) * 8;
        ly0[threadIdx.x]  = o[0];
        lx0[threadIdx.x]  = o[1];
        ls[threadIdx.x]   = o[2];
        lact[threadIdx.x] = o[3];
    }
    __syncthreads();

    float sf = (float)s;
    float ty = (float)HP_ / sf;       // Hp / sf  (f32 divide, matches reference)
    float tx = (float)WP_ / sf;       // Wp / sf
    int total = s * s;
    float* imgout = out + (size_t)b * IMG_FLOATS;

    for (int idx = threadIdx.x; idx < total; idx += 256) {
        int py = idx / s;
        int px = idx - py * s;
        int gy = y0 + py;
        int gx = x0 + px;
        if (gy < 0 || gy >= H_ || gx < 0 || gx >= W_) continue;

        // skip if a LATER valid box also covers this pixel (last write wins)
        bool covered = false;
        for (int m = n + 1; m < N_; ++m) {
            if (lact[m]) {
                int ry = gy - ly0[m];
                int rx = gx - lx0[m];
                if (ry >= 0 && ry < ls[m] && rx >= 0 && rx < ls[m]) { covered = true; break; }
            }
        }
        if (covered) continue;

        // invert transforms: flip_ud, flip_lr, then rot90 (CCW)
        int iy2 = d2 ? (s - 1 - py) : py;
        int ix2 = d1 ? (s - 1 - px) : px;
        int ry  = d0 ? ix2 : iy2;
        int rx  = d0 ? (s - 1 - iy2) : ix2;

        // half-pixel-center resize map + bilinear (tf v2 semantics)
        float sy = ((float)ry + 0.5f) * ty - 0.5f;
        float sx = ((float)rx + 0.5f) * tx - 0.5f;
        sy = fminf(fmaxf(sy, 0.0f), (float)(HP_ - 1));
        sx = fminf(fmaxf(sx, 0.0f), (float)(WP_ - 1));
        int yy0 = (int)floorf(sy);
        int xx0 = (int)floorf(sx);
        int yy1 = yy0 + 1 < HP_ - 1 ? yy0 + 1 : HP_ - 1;
        int xx1 = xx0 + 1 < WP_ - 1 ? xx0 + 1 : WP_ - 1;
        float wy = sy - (float)yy0;
        float wx = sx - (float)xx0;

        const float* p00 = patch + (yy0 * WP_ + xx0) * 3;
        const float* p01 = patch + (yy0 * WP_ + xx1) * 3;
        const float* p10 = patch + (yy1 * WP_ + xx0) * 3;
        const float* p11 = patch + (yy1 * WP_ + xx1) * 3;
        float* o = imgout + ((size_t)gy * W_ + gx) * 3;
        #pragma unroll
        for (int c = 0; c < 3; ++c) {
            float top = p00[c] * (1.0f - wx) + p01[c] * wx;
            float bot = p10[c] * (1.0f - wx) + p11[c] * wx;
            o[c] = top * (1.0f - wy) + bot * wy;
        }
    }
}

extern "C" void kernel_launch(void* const* d_in, const int* in_sizes, int n_in,
                              void* d_out, int out_size, void* d_ws, size_t ws_size,
                              hipStream_t stream) {
    const float*         boxes   = (const float*)d_in[0];          // [16,16,4]
    const float*         images  = (const float*)d_in[1];          // [16,640,640,3]
    const float*         patch   = (const float*)d_in[2];          // [300,300,3]
    const unsigned char* dec_raw = (const unsigned char*)d_in[3];  // [16,16,3] (layout detected)

    float* out    = (float*)d_out;
    float* pboxes = out + PBOX_OFF;
    int*   info   = (int*)d_ws;   // 256*8 ints = 8 KiB

    prep_kernel<<<1, 256, 0, stream>>>(boxes, dec_raw, pboxes, info);

    int n4 = ALL_FLOATS / 4;      // 4,915,200 float4 elements
    copy_kernel<<<2048, 256, 0, stream>>>((const float4*)images, (float4*)out, n4);

    patch_kernel<<<B_ * N_, 256, 0, stream>>>(patch, info, out);
}

// Round 2
// 162.894 us; speedup vs baseline: 1.2778x; 1.2778x over previous
//
#include <hip/hip_runtime.h>
#include <hip/hip_bf16.h>

#define B_  16
#define N_  16
#define H_  640
#define W_  640
#define HP_ 300
#define WP_ 300
#define IMG_FLOATS (H_ * W_ * 3)          // 1,228,800 per image
#define ALL_FLOATS (B_ * IMG_FLOATS)      // 19,660,800
#define PBOX_OFF   ALL_FLOATS
#define QUADS_PER_IMG (H_ * W_ / 4)       // 102,400
#define BLOCKS_PER_IMG (QUADS_PER_IMG / 256)  // 400

// boxinfo layout in d_ws: per entry e in [0,256): 8 ints
//   [0]=y0i [1]=x0i [2]=s [3]=valid [4]=d0(rot90) [5]=d1(flip_lr) [6]=d2(flip_ud) [7]=pad

__global__ __launch_bounds__(256) void prep_kernel(
    const float* __restrict__ boxes,           // [B,N,4] ymin,xmin,h,w
    const unsigned char* __restrict__ dec_raw, // [B,N,3] bool/int32/float32 (detected)
    float* __restrict__ pboxes_out,            // d_out + PBOX_OFF, [B,N,4]
    int* __restrict__ info)                    // d_ws, 256*8 ints
{
    __shared__ int s_nonzero_off;  // any nonzero byte at i%4 != 0
    __shared__ int s_floatpat;     // any byte == 0x3F or 0x80 (f32 1.0 pattern)
    if (threadIdx.x == 0) { s_nonzero_off = 0; s_floatpat = 0; }
    __syncthreads();
    for (int i = threadIdx.x; i < B_ * N_ * 3; i += blockDim.x) {
        unsigned char by = dec_raw[i];
        if ((i & 3) != 0 && by != 0) atomicOr(&s_nonzero_off, 1);
        if (by == 0x3F || by == 0x80) atomicOr(&s_floatpat, 1);
    }
    __syncthreads();
    int mode;                    // 0 = 1-byte bool, 1 = int32, 2 = float32
    if (!s_nonzero_off)      mode = 1;
    else if (s_floatpat)     mode = 2;
    else                     mode = 0;

    int t = threadIdx.x;
    if (t < B_ * N_) {
        float ymin = boxes[t * 4 + 0];
        float xmin = boxes[t * 4 + 1];
        float h    = boxes[t * 4 + 2];
        float w    = boxes[t * 4 + 3];
        float ph = h * 0.2f;
        float pw = 1.0f * ph;                 // ASPECT = 1
        float y0 = ymin + h * 0.5f;           // ORIGIN[1]
        float x0 = xmin + w * 0.5f;           // ORIGIN[0]
        if (y0 + ph > (float)H_) y0 = (float)H_ - ph;
        if (x0 + pw > (float)W_) x0 = (float)W_ - pw;
        pboxes_out[t * 4 + 0] = y0;
        pboxes_out[t * 4 + 1] = x0;
        pboxes_out[t * 4 + 2] = ph;
        pboxes_out[t * 4 + 3] = pw;

        int y0i = (int)y0;                    // tf.cast truncation
        int x0i = (int)x0;
        int phi = (int)ph;
        int pwi = (int)pw;
        int valid = (phi * pwi) > 400;        // AREA_THRESH
        int s = phi > 1 ? phi : 1;

        int d0, d1, d2;
        if (mode == 0) {
            d0 = dec_raw[t * 3 + 0] != 0;
            d1 = dec_raw[t * 3 + 1] != 0;
            d2 = dec_raw[t * 3 + 2] != 0;
        } else if (mode == 1) {
            const int* di = (const int*)dec_raw;
            d0 = di[t * 3 + 0] != 0;
            d1 = di[t * 3 + 1] != 0;
            d2 = di[t * 3 + 2] != 0;
        } else {
            const float* df = (const float*)dec_raw;
            d0 = df[t * 3 + 0] != 0.0f;
            d1 = df[t * 3 + 1] != 0.0f;
            d2 = df[t * 3 + 2] != 0.0f;
        }
        int* e = info + t * 8;
        e[0] = y0i; e[1] = x0i; e[2] = s; e[3] = valid;
        e[4] = d0;  e[5] = d1;  e[6] = d2; e[7] = 0;
    }
}

// One pass over all pixels: copy OR bilinear-sample from the last covering box.
__global__ __launch_bounds__(256) void fused_kernel(
    const float*  __restrict__ images,  // [B,H,W,3]
    const float*  __restrict__ patch,   // [300,300,3]
    const int*    __restrict__ info,    // 256*8 ints
    float*        __restrict__ out)     // [B,H,W,3]
{
    int b = blockIdx.x / BLOCKS_PER_IMG;
    int q = (blockIdx.x - b * BLOCKS_PER_IMG) * 256 + threadIdx.x; // quad in image
    int gy = q / (W_ / 4);
    int gx0 = (q - gy * (W_ / 4)) * 4;

    // per-image box table in LDS
    __shared__ int ly0[N_], lx0[N_], ls[N_], lfl[N_];
    if (threadIdx.x < N_) {
        const int* o = info + (b * N_ + threadIdx.x) * 8;
        ly0[threadIdx.x] = o[0];
        lx0[threadIdx.x] = o[1];
        ls[threadIdx.x]  = o[2];
        lfl[threadIdx.x] = o[3] | (o[4] << 1) | (o[5] << 2) | (o[6] << 3);
    }
    __syncthreads();

    size_t base = (size_t)b * IMG_FLOATS + (size_t)q * 12;

    // 12 floats = 4 pixels (16B-aligned: 48*q bytes)
    float vals[12];
    *(float4*)&vals[0] = *(const float4*)(images + base);
    *(float4*)&vals[4] = *(const float4*)(images + base + 4);
    *(float4*)&vals[8] = *(const float4*)(images + base + 8);

    #pragma unroll
    for (int p = 0; p < 4; ++p) {
        int gx = gx0 + p;
        // highest-index valid covering box == last write in the reference scan
        int hit = -1;
        for (int m = N_ - 1; m >= 0; --m) {
            if (lfl[m] & 1) {
                unsigned ry = (unsigned)(gy - ly0[m]);
                unsigned rx = (unsigned)(gx - lx0[m]);
                if (ry < (unsigned)ls[m] && rx < (unsigned)ls[m]) { hit = m; break; }
            }
        }
        if (hit >= 0) {
            int s  = ls[hit];
            int fl = lfl[hit];
            int py = gy - ly0[hit];
            int px = gx - lx0[hit];
            // invert transforms: flip_ud, flip_lr, then rot90 (CCW)
            int iy2 = (fl & 8) ? (s - 1 - py) : py;   // d2
            int ix2 = (fl & 4) ? (s - 1 - px) : px;   // d1
            int ry  = (fl & 2) ? ix2 : iy2;           // d0
            int rx  = (fl & 2) ? (s - 1 - iy2) : ix2;

            float sf = (float)s;
            float sy = ((float)ry + 0.5f) * ((float)HP_ / sf) - 0.5f;
            float sx = ((float)rx + 0.5f) * ((float)WP_ / sf) - 0.5f;
            sy = fminf(fmaxf(sy, 0.0f), (float)(HP_ - 1));
            sx = fminf(fmaxf(sx, 0.0f), (float)(WP_ - 1));
            int yy0 = (int)floorf(sy);
            int xx0 = (int)floorf(sx);
            int yy1 = yy0 + 1 < HP_ - 1 ? yy0 + 1 : HP_ - 1;
            int xx1 = xx0 + 1 < WP_ - 1 ? xx0 + 1 : WP_ - 1;
            float wy = sy - (float)yy0;
            float wx = sx - (float)xx0;

            const float* p00 = patch + (yy0 * WP_ + xx0) * 3;
            const float* p01 = patch + (yy0 * WP_ + xx1) * 3;
            const float* p10 = patch + (yy1 * WP_ + xx0) * 3;
            const float* p11 = patch + (yy1 * WP_ + xx1) * 3;
            #pragma unroll
            for (int c = 0; c < 3; ++c) {
                float top = p00[c] * (1.0f - wx) + p01[c] * wx;
                float bot = p10[c] * (1.0f - wx) + p11[c] * wx;
                vals[p * 3 + c] = top * (1.0f - wy) + bot * wy;
            }
        }
    }

    *(float4*)(out + base)     = *(float4*)&vals[0];
    *(float4*)(out + base + 4) = *(float4*)&vals[4];
    *(float4*)(out + base + 8) = *(float4*)&vals[8];
}

extern "C" void kernel_launch(void* const* d_in, const int* in_sizes, int n_in,
                              void* d_out, int out_size, void* d_ws, size_t ws_size,
                              hipStream_t stream) {
    const float*         boxes   = (const float*)d_in[0];          // [16,16,4]
    const float*         images  = (const float*)d_in[1];          // [16,640,640,3]
    const float*         patch   = (const float*)d_in[2];          // [300,300,3]
    const unsigned char* dec_raw = (const unsigned char*)d_in[3];  // [16,16,3]

    float* out    = (float*)d_out;
    float* pboxes = out + PBOX_OFF;
    int*   info   = (int*)d_ws;   // 256*8 ints = 8 KiB

    prep_kernel<<<1, 256, 0, stream>>>(boxes, dec_raw, pboxes, info);
    fused_kernel<<<B_ * BLOCKS_PER_IMG, 256, 0, stream>>>(images, patch, info, out);
}